// Round 15
// baseline (144.351 us; speedup 1.0000x reference)
//
#include <hip/hip_runtime.h>
#include <math.h>

// Problem constants
#define B_  4
#define N_  170
#define T_  96
#define D_  256
#define H_  8
#define HD_ 32
#define BN_ (B_*N_)       // 680 (bn) blocks
#define WSZ (D_*D_)       // 65536 per weight matrix

typedef short  bf16x8 __attribute__((ext_vector_type(8)));
typedef float  f32x4  __attribute__((ext_vector_type(4)));

// ---- LDS map (bytes). All tiles use 256B sub-planes: [..][kgl][lr][16B] ----
// Region lifetimes (one barrier between every last-read and first-write):
//   XB: Xq (P0-P1) -> Xv (P2-P3) -> P scratch (P4) -> O planes (P5-P6)
//   KB: Xk (P1-P2) -> K planes (P3-P4)
//   VB: q planes (P1-P2) -> V planes (P3-P4)
#define XB   0
#define KB   49152
#define VB   98304
#define LDSZ 147456

__device__ __forceinline__ ushort to_bf16(float x)
{
    uint u = __builtin_bit_cast(uint, x);
    u += 0x8000u;                      // round-half-up
    return (ushort)(u >> 16);
}

__device__ __forceinline__ uint pack2(float x0, float x1)
{
    return (uint)to_bf16(x0) | ((uint)to_bf16(x1) << 16);
}

__device__ __forceinline__ uint4 pack8(float4 a0, float4 a1)
{
    uint4 r;
    r.x = pack2(a0.x, a0.y); r.y = pack2(a0.z, a0.w);
    r.z = pack2(a1.x, a1.y); r.w = pack2(a1.z, a1.w);
    return r;
}

#define MFMA(a, b, c) __builtin_amdgcn_mfma_f32_16x16x32_bf16((a), (b), (c), 0, 0, 0)
// phase-top fence for asm-pinned loads: HW wait + compiler motion fence (rule #18)
#define WAITW do { \
        asm volatile("s_waitcnt vmcnt(0)" ::: "memory"); \
        __builtin_amdgcn_sched_barrier(0); \
    } while (0)

// ---------------------------------------------------------------------------
// Kernel 0: W prep. W[col][k] fp32 -> single ROUNDED bf16, chunked layout
// [k/8][col][8] per matrix. Wq gets 1/sqrt(32) folded in. 0=Wq 1=Wk 2=Wv 3=Wo.
// ---------------------------------------------------------------------------
__global__ __launch_bounds__(256)
void splitw_kernel(const float* __restrict__ Wq, const float* __restrict__ Wk,
                   const float* __restrict__ Wv, const float* __restrict__ Wo,
                   ushort* __restrict__ whi)
{
    const int gid = blockIdx.x * 256 + threadIdx.x;   // 32768 chunks
    const int mat = gid >> 13;
    const int rem = gid & 8191;
    const int col = rem >> 5;
    const int kc  = rem & 31;
    const float* W = (mat == 0) ? Wq : (mat == 1) ? Wk : (mat == 2) ? Wv : Wo;
    const float s  = (mat == 0) ? 0.17677669529663687f : 1.0f;
    const float* p = W + (size_t)col * D_ + kc * 8;
    float4 a0 = *(const float4*)p;
    float4 a1 = *(const float4*)(p + 4);
    a0.x *= s; a0.y *= s; a0.z *= s; a0.w *= s;
    a1.x *= s; a1.y *= s; a1.z *= s; a1.w *= s;
    const size_t off = (size_t)mat * WSZ + ((size_t)kc * 256 + col) * 8;
    *(uint4*)(whi + off) = pack8(a0, a1);
}

// ---------------------------------------------------------------------------
// Mega kernel: one block per bn. 1024 threads = 16 waves.
// GEMM partition: wave (dp = wv>>1, th = wv&1) owns d-tiles {2dp, 2dp+1} x
// t-tiles {3th..3th+2} -> each X-fragment LDS read feeds 2 MFMAs (halves the
// dominant LDS-read term). W fragments (16 x b128 = 64 VGPR) are loaded via
// asm-pinned global_load_dwordx4 ONE PHASE AHEAD: asm "=v" cannot be sunk or
// rematerialized, and the untracked loads fly across barriers (T4-style);
// the consuming phase opens with vmcnt(0) + sched_barrier(0).
// Attention: head dp, row-half th; K fragments hoisted (3x reuse).
// ---------------------------------------------------------------------------
__global__ __launch_bounds__(1024)
void mega_kernel(const float* __restrict__ Xq, const float* __restrict__ Xk,
                 const float* __restrict__ Xv, const ushort* __restrict__ W,
                 const float* __restrict__ bq, const float* __restrict__ bk,
                 const float* __restrict__ bv, const float* __restrict__ bo,
                 float* __restrict__ out)
{
    __shared__ __align__(16) char lds[LDSZ];

    const int bn   = blockIdx.x;
    const int tid  = threadIdx.x;
    const int wv   = tid >> 6;       // 0..15
    const int lane = tid & 63;
    const int lr   = lane & 15;
    const int kgl  = lane >> 4;
    const int dp   = wv >> 1;        // d-tile pair / attention head
    const int th   = wv & 1;         // t-half
    const int ib   = th * 3;         // attention irow base
    const size_t xoff = (size_t)bn * T_ * D_;

    // staging chunk coords: 3 chunks/thread (chunk = 8 elems)
    int srow[3], skc[3]; uint saddr[3];
    #pragma unroll
    for (int c = 0; c < 3; c++) {
        const int cc = tid + c * 1024;
        const int row = cc % 96, kc = cc / 96;
        srow[c] = row; skc[c] = kc;
        saddr[c] = (uint)(((((kc >> 2) * 6 + (row >> 4)) * 4 + (kc & 3)) * 256)
                          + (row & 15) * 16);
    }

    bf16x8 w0[8], w1[8];   // asm-pinned W fragments for the 2 owned d-tiles

    // issue 16 asm loads (d-tile pair shares a base; u=1 is +256B imm offset)
#define LOADW(matbase) do { \
        _Pragma("unroll") \
        for (int ks_ = 0; ks_ < 8; ks_++) { \
            const ushort* pw_ = (matbase) + ((size_t)(ks_*4+kgl)*256 + dp*32 + lr)*8; \
            asm volatile("global_load_dwordx4 %0, %1, off" \
                         : "=v"(w0[ks_]) : "v"(pw_)); \
            asm volatile("global_load_dwordx4 %0, %1, off offset:256" \
                         : "=v"(w1[ks_]) : "v"(pw_)); \
        } \
    } while (0)

    // ---- P0: stage Xq -> XB; prefetch Xk into regs; issue Wq ----
    #pragma unroll
    for (int c = 0; c < 3; c++) {
        const float* p = Xq + xoff + srow[c] * D_ + skc[c] * 8;
        float4 a0 = *(const float4*)p, a1 = *(const float4*)(p + 4);
        *(uint4*)(lds + XB + saddr[c]) = pack8(a0, a1);
    }
    float4 pf[6];
    #pragma unroll
    for (int c = 0; c < 3; c++) {
        const float* p = Xk + xoff + srow[c] * D_ + skc[c] * 8;
        pf[2*c] = *(const float4*)p; pf[2*c+1] = *(const float4*)(p + 4);
    }
    LOADW(W);
    __syncthreads();                               // (0)

    // ---- P1: write Xk -> KB; q-GEMM(XB, Wq) + q-epi -> VB; pf Xv; Wk ----
    WAITW;
    #pragma unroll
    for (int c = 0; c < 3; c++)
        *(uint4*)(lds + KB + saddr[c]) = pack8(pf[2*c], pf[2*c+1]);
    {
        f32x4 acc[2][3];
        #pragma unroll
        for (int u = 0; u < 2; u++)
            #pragma unroll
            for (int v = 0; v < 3; v++) acc[u][v] = (f32x4)0.f;
        #pragma unroll
        for (int ks = 0; ks < 8; ks++)
            #pragma unroll
            for (int v = 0; v < 3; v++) {
                bf16x8 xb = *(const bf16x8*)(lds + XB + ((ks*6 + th*3 + v)*4+kgl)*256 + lr*16);
                acc[0][v] = MFMA(w0[ks], xb, acc[0][v]);
                acc[1][v] = MFMA(w1[ks], xb, acc[1][v]);
            }
        // q epilogue: + s*bq -> bf16 q-planes in VB (K-style layout), h = dp
        const float qs = 0.17677669529663687f;
        #pragma unroll
        for (int u = 0; u < 2; u++) {
            const int mt = dp*2 + u;
            const int kg = u*2 + (kgl >> 1);
            float4 b4 = *(const float4*)(bq + mt*16 + kgl*4);
            #pragma unroll
            for (int v = 0; v < 3; v++) {
                const int nt = th*3 + v;
                ushort4 o;
                o.x = to_bf16(acc[u][v][0] + b4.x*qs);
                o.y = to_bf16(acc[u][v][1] + b4.y*qs);
                o.z = to_bf16(acc[u][v][2] + b4.z*qs);
                o.w = to_bf16(acc[u][v][3] + b4.w*qs);
                *(ushort4*)(lds + VB + ((dp*6+nt)*4+kg)*256 + lr*16 + (kgl&1)*8) = o;
            }
        }
    }
    #pragma unroll
    for (int c = 0; c < 3; c++) {
        const float* p = Xv + xoff + srow[c] * D_ + skc[c] * 8;
        pf[2*c] = *(const float4*)p; pf[2*c+1] = *(const float4*)(p + 4);
    }
    LOADW(W + WSZ);
    __syncthreads();                               // (1)

    // ---- P2: write Xv -> XB; k-GEMM(KB, Wk); qf pull(VB); issue Wv ----
    WAITW;
    #pragma unroll
    for (int c = 0; c < 3; c++)
        *(uint4*)(lds + XB + saddr[c]) = pack8(pf[2*c], pf[2*c+1]);
    f32x4 kacc[2][3];
    {
        #pragma unroll
        for (int u = 0; u < 2; u++)
            #pragma unroll
            for (int v = 0; v < 3; v++) kacc[u][v] = (f32x4)0.f;
        #pragma unroll
        for (int ks = 0; ks < 8; ks++)
            #pragma unroll
            for (int v = 0; v < 3; v++) {
                bf16x8 xb = *(const bf16x8*)(lds + KB + ((ks*6 + th*3 + v)*4+kgl)*256 + lr*16);
                kacc[0][v] = MFMA(w0[ks], xb, kacc[0][v]);
                kacc[1][v] = MFMA(w1[ks], xb, kacc[1][v]);
            }
    }
    bf16x8 qf[3];
    #pragma unroll
    for (int j = 0; j < 3; j++)
        qf[j] = *(const bf16x8*)(lds + VB + ((dp*6 + ib + j)*4 + kgl)*256 + lr*16);
    LOADW(W + 2*WSZ);
    __syncthreads();                               // (2)

    // ---- P3: k-epi -> KB (Xk dead); v-GEMM(XB, Wv) + v-epi -> VB ----
    WAITW;
    #pragma unroll
    for (int u = 0; u < 2; u++) {
        const int mt = dp*2 + u;
        const int kg = u*2 + (kgl >> 1);
        float4 b4 = *(const float4*)(bk + mt*16 + kgl*4);
        #pragma unroll
        for (int v = 0; v < 3; v++) {
            const int nt = th*3 + v;
            ushort4 o;
            o.x = to_bf16(kacc[u][v][0] + b4.x);
            o.y = to_bf16(kacc[u][v][1] + b4.y);
            o.z = to_bf16(kacc[u][v][2] + b4.z);
            o.w = to_bf16(kacc[u][v][3] + b4.w);
            *(ushort4*)(lds + KB + ((dp*6+nt)*4+kg)*256 + lr*16 + (kgl&1)*8) = o;
        }
    }
    {
        f32x4 av[2][3];
        #pragma unroll
        for (int u = 0; u < 2; u++)
            #pragma unroll
            for (int v = 0; v < 3; v++) av[u][v] = (f32x4)0.f;
        #pragma unroll
        for (int ks = 0; ks < 8; ks++)
            #pragma unroll
            for (int v = 0; v < 3; v++) {
                bf16x8 xa = *(const bf16x8*)(lds + XB + ((ks*6 + th*3 + v)*4+kgl)*256 + lr*16);
                av[0][v] = MFMA(xa, w0[ks], av[0][v]);
                av[1][v] = MFMA(xa, w1[ks], av[1][v]);
            }
        // v epilogue: d-col tile dp*2+u -> head dp, hd-half u
        #pragma unroll
        for (int u = 0; u < 2; u++) {
            const float bvv = bv[(dp*2+u)*16 + lr];
            #pragma unroll
            for (int v = 0; v < 3; v++) {
                const int mt = th*3 + v;
                const int kvkg = mt*2 + (kgl >> 1);
                const int s2 = kvkg >> 2, kgv = kvkg & 3;
                ushort4 o;
                o.x = to_bf16(av[u][v][0] + bvv);
                o.y = to_bf16(av[u][v][1] + bvv);
                o.z = to_bf16(av[u][v][2] + bvv);
                o.w = to_bf16(av[u][v][3] + bvv);
                *(ushort4*)(lds + VB + (((dp*3+s2)*2+u)*4+kgv)*256 + lr*16 + (kgl&1)*8) = o;
            }
        }
    }
    __syncthreads();                               // (3)

    // ---- P4: attention. head dp, 3 q-row tiles; K frags hoisted (3x);
    //      swapped QK^T, in-reg softmax, P via per-wave 3KB XB scratch, PV.
    //      Wo issued AFTER PV (keeps W block out of the register peak). ----
    f32x4 oacc[3][2];
    #pragma unroll
    for (int j = 0; j < 3; j++) { oacc[j][0] = (f32x4)0.f; oacc[j][1] = (f32x4)0.f; }
    {
        char* sw = lds + XB + wv * 3072;           // 12 planes x 256B
        bf16x8 kf[6];
        #pragma unroll
        for (int mt = 0; mt < 6; mt++)
            kf[mt] = *(const bf16x8*)(lds + KB + ((dp*6+mt)*4+kgl)*256 + lr*16);
        #pragma unroll
        for (int j = 0; j < 3; j++) {
            f32x4 s[6];
            #pragma unroll
            for (int mt = 0; mt < 6; mt++)
                s[mt] = MFMA(kf[mt], qf[j], (f32x4)0.f);   // rows kv, col q = lr
            float mx = s[0][0];
            #pragma unroll
            for (int mt = 0; mt < 6; mt++)
                #pragma unroll
                for (int r = 0; r < 4; r++) mx = fmaxf(mx, s[mt][r]);
            mx = fmaxf(mx, __shfl_xor(mx, 16));
            mx = fmaxf(mx, __shfl_xor(mx, 32));
            float sum = 0.f;
            #pragma unroll
            for (int mt = 0; mt < 6; mt++)
                #pragma unroll
                for (int r = 0; r < 4; r++) {
                    float e = __expf(s[mt][r] - mx);
                    s[mt][r] = e; sum += e;
                }
            sum += __shfl_xor(sum, 16);
            sum += __shfl_xor(sum, 32);
            const float inv = 1.f / sum;
            #pragma unroll
            for (int mt = 0; mt < 6; mt++) {
                uint2 u2;
                u2.x = pack2(s[mt][0]*inv, s[mt][1]*inv);
                u2.y = pack2(s[mt][2]*inv, s[mt][3]*inv);
                *(uint2*)(sw + (mt*2 + (kgl>>1))*256 + lr*16 + (kgl&1)*8) = u2;
            }
            #pragma unroll
            for (int s2 = 0; s2 < 3; s2++) {
                bf16x8 pa = *(const bf16x8*)(sw + (s2*4+kgl)*256 + lr*16);
                #pragma unroll
                for (int n2 = 0; n2 < 2; n2++) {
                    bf16x8 vf = *(const bf16x8*)(lds + VB + (((dp*3+s2)*2+n2)*4+kgl)*256 + lr*16);
                    oacc[j][n2] = MFMA(pa, vf, oacc[j][n2]);
                }
            }
        }
    }
    LOADW(W + 3*WSZ);   // Wo: flies across bar(4), P5, bar(5)
    __syncthreads();                               // (4) scratch dead

    // ---- P5: O -> XB planes (X layout), bf16 ----
    #pragma unroll
    for (int j = 0; j < 3; j++)
        #pragma unroll
        for (int n2 = 0; n2 < 2; n2++) {
            const int dcol = dp*32 + n2*16 + lr;
            const int kc   = dcol >> 3;            // 0..31
            const int irow = ib + j;
            char* base = lds + XB + (((kc>>2)*6 + irow)*4 + (kc&3))*256 + (dcol&7)*2;
            #pragma unroll
            for (int r = 0; r < 4; r++)
                *(ushort*)(base + (kgl*4+r)*16) = to_bf16(oacc[j][n2][r]);
        }
    __syncthreads();                               // (5)

    // ---- P6: wo GEMM(XB, Wo) -> d_out fp32 + bo ----
    WAITW;
    {
        f32x4 a2[2][3];
        #pragma unroll
        for (int u = 0; u < 2; u++)
            #pragma unroll
            for (int v = 0; v < 3; v++) a2[u][v] = (f32x4)0.f;
        #pragma unroll
        for (int ks = 0; ks < 8; ks++)
            #pragma unroll
            for (int v = 0; v < 3; v++) {
                bf16x8 oa = *(const bf16x8*)(lds + XB + ((ks*6 + th*3 + v)*4+kgl)*256 + lr*16);
                a2[0][v] = MFMA(oa, w0[ks], a2[0][v]);
                a2[1][v] = MFMA(oa, w1[ks], a2[1][v]);
            }
        #pragma unroll
        for (int u = 0; u < 2; u++) {
            const int col = (dp*2+u)*16 + lr;
            const float bod = bo[col];
            #pragma unroll
            for (int v = 0; v < 3; v++) {
                const int mt = th*3 + v;
                #pragma unroll
                for (int r = 0; r < 4; r++) {
                    const int t = mt*16 + kgl*4 + r;
                    out[((size_t)(bn*T_ + t))*D_ + col] = a2[u][v][r] + bod;
                }
            }
        }
    }
#undef LOADW
}

// ---------------------------------------------------------------------------
extern "C" void kernel_launch(void* const* d_in, const int* in_sizes, int n_in,
                              void* d_out, int out_size, void* d_ws, size_t ws_size,
                              hipStream_t stream)
{
    const float* query = (const float*)d_in[0];
    const float* key   = (const float*)d_in[1];
    const float* value = (const float*)d_in[2];
    // d_in[3..5]: pattern_matrix, Wp, bp -- mathematically a no-op (mask == 1)
    const float* Wq = (const float*)d_in[6];
    const float* bq = (const float*)d_in[7];
    const float* Wk = (const float*)d_in[8];
    const float* bk = (const float*)d_in[9];
    const float* Wv = (const float*)d_in[10];
    const float* bv = (const float*)d_in[11];
    const float* Wo = (const float*)d_in[12];
    const float* bo = (const float*)d_in[13];

    float*  out = (float*)d_out;
    ushort* whi = (ushort*)d_ws;   // 4 matrices, chunked bf16: 512 KB

    splitw_kernel<<<dim3(128), 256, 0, stream>>>(Wq, Wk, Wv, Wo, whi);
    mega_kernel<<<dim3(BN_), 1024, 0, stream>>>(
        query, key, value, whi, bq, bk, bv, bo, out);
}

// Round 16
// 133.904 us; speedup vs baseline: 1.0780x; 1.0780x over previous
//
#include <hip/hip_runtime.h>
#include <math.h>

// Problem constants
#define B_  4
#define N_  170
#define T_  96
#define D_  256
#define H_  8
#define HD_ 32
#define BN_ (B_*N_)       // 680 (bn) blocks
#define WSZ (D_*D_)       // 65536 per weight matrix

typedef short  bf16x8 __attribute__((ext_vector_type(8)));
typedef float  f32x4  __attribute__((ext_vector_type(4)));
typedef float  f32x16 __attribute__((ext_vector_type(16)));

// ---- LDS map (bytes). 256B sub-planes, canonical element maps ----
//   X layout: chunk(row,kc) at (((kc>>2)*6+(row>>4))*4+(kc&3))*256+(row&15)*16
//   K/q: (h,t,hd) at ((h*6+(t>>4))*4+(hd>>3))*256+(t&15)*16+(hd&7)*2
//   V:   (h,t,hd) at (((h*3+(t>>5))*2+(hd>>4))*4+((t>>3)&3))*256+(hd&15)*16+(t&7)*2
// Region lifetimes: XB: Xq->Xv->P scratch->O planes; KB: Xk->K planes;
// VB: q planes->V planes
#define XB   0
#define KB   49152
#define VB   98304
#define LDSZ 147456

__device__ __forceinline__ ushort to_bf16(float x)
{
    uint u = __builtin_bit_cast(uint, x);
    u += 0x8000u;                      // round-half-up
    return (ushort)(u >> 16);
}

__device__ __forceinline__ uint pack2(float x0, float x1)
{
    return (uint)to_bf16(x0) | ((uint)to_bf16(x1) << 16);
}

__device__ __forceinline__ uint4 pack8(float4 a0, float4 a1)
{
    uint4 r;
    r.x = pack2(a0.x, a0.y); r.y = pack2(a0.z, a0.w);
    r.z = pack2(a1.x, a1.y); r.w = pack2(a1.z, a1.w);
    return r;
}

#define MFMA16(a, b, c) __builtin_amdgcn_mfma_f32_16x16x32_bf16((a), (b), (c), 0, 0, 0)
#define MFMA32(a, b, c) __builtin_amdgcn_mfma_f32_32x32x16_bf16((a), (b), (c), 0, 0, 0)

// ---------------------------------------------------------------------------
// Kernel 0: W prep. W[col][k] fp32 -> single ROUNDED bf16, chunked layout
// [k/8][col][8] per matrix. Wq gets 1/sqrt(32) folded in. 0=Wq 1=Wk 2=Wv 3=Wo.
// ---------------------------------------------------------------------------
__global__ __launch_bounds__(256)
void splitw_kernel(const float* __restrict__ Wq, const float* __restrict__ Wk,
                   const float* __restrict__ Wv, const float* __restrict__ Wo,
                   ushort* __restrict__ whi)
{
    const int gid = blockIdx.x * 256 + threadIdx.x;   // 32768 chunks
    const int mat = gid >> 13;
    const int rem = gid & 8191;
    const int col = rem >> 5;
    const int kc  = rem & 31;
    const float* W = (mat == 0) ? Wq : (mat == 1) ? Wk : (mat == 2) ? Wv : Wo;
    const float s  = (mat == 0) ? 0.17677669529663687f : 1.0f;
    const float* p = W + (size_t)col * D_ + kc * 8;
    float4 a0 = *(const float4*)p;
    float4 a1 = *(const float4*)(p + 4);
    a0.x *= s; a0.y *= s; a0.z *= s; a0.w *= s;
    a1.x *= s; a1.y *= s; a1.z *= s; a1.w *= s;
    const size_t off = (size_t)mat * WSZ + ((size_t)kc * 256 + col) * 8;
    *(uint4*)(whi + off) = pack8(a0, a1);
}

// ---------------------------------------------------------------------------
// Mega kernel: one block per bn. 1024 threads = 16 waves.
// GEMMs use 32x32x16 MFMA (2x FLOP per operand byte -> halves GEMM LDS reads).
// 24 output tiles (8 d-tiles x 3 t-tiles of 32): heavy waves (wv<8) own
// (dt=wv, tt in {0,2}) sharing one W-frag; light waves own (dt=wv&7, tt=1).
// Per-SIMD balanced (2 heavy + 2 light). C/D 32x32 layout: col=lane&31,
// row=(reg&3)+8*(reg>>2)+4*(lane>>5)  [m74/m101].
// Attention (16x16) + staging + region rotation: R14-verbatim.
// ---------------------------------------------------------------------------
__global__ __launch_bounds__(1024)
void mega_kernel(const float* __restrict__ Xq, const float* __restrict__ Xk,
                 const float* __restrict__ Xv, const ushort* __restrict__ W,
                 const float* __restrict__ bq, const float* __restrict__ bk,
                 const float* __restrict__ bv, const float* __restrict__ bo,
                 float* __restrict__ out)
{
    __shared__ __align__(16) char lds[LDSZ];

    const int bn   = blockIdx.x;
    const int tid  = threadIdx.x;
    const int wv   = tid >> 6;       // 0..15
    const int lane = tid & 63;
    const int lr   = lane & 15;
    const int kgl  = lane >> 4;      // 0..3 (attention indexing)
    const int l31  = lane & 31;
    const int l5   = lane >> 5;      // 0..1 (32-wide k-half)
    const int l4   = kgl & 1;
    const int h    = wv >> 1;        // attention head
    const int ib   = (wv & 1) * 3;   // attention irow base
    const bool heavy = (wv < 8);
    const int dt   = wv & 7;         // GEMM d-tile (== head, 32 cols)
    const int tt0  = heavy ? 0 : 1;  // heavy also does tt=2
    const size_t xoff = (size_t)bn * T_ * D_;

    // staging chunk coords: 3 chunks/thread (chunk = 8 elems)
    int srow[3], skc[3]; uint saddr[3];
    #pragma unroll
    for (int c = 0; c < 3; c++) {
        const int cc = tid + c * 1024;
        const int row = cc % 96, kc = cc / 96;
        srow[c] = row; skc[c] = kc;
        saddr[c] = (uint)(((((kc >> 2) * 6 + (row >> 4)) * 4 + (kc & 3)) * 256)
                          + (row & 15) * 16);
    }

// 32-wide fragment reads. X-frag: row = tt*32+l31, kc = ks*2+l5 (X layout).
#define XFRAG(base, tt_, ks_) \
    (*(const bf16x8*)(lds + (base) + \
        ((((ks_) >> 1) * 24 + ((tt_) * 2 + l4) * 4 + (((ks_) & 1) * 2 + l5)) * 256) \
        + lr * 16))
// W-frag: lane l -> W[d = dt*32+l31][k = ks*16 + l5*8 ..+7] (chunked layout)
#define WFRAG(mat, ks_) \
    (*(const bf16x8*)((mat) + ((size_t)((ks_) * 2 + l5) * 256 + dt * 32 + l31) * 8))
// q/k epilogue: C[d=dt*32+8g+4*l5+r][t=tt*32+l31] -> K-style planes at RB
#define QK_EPI(ACC, tt_, bp, sc, RB) do { \
        _Pragma("unroll") \
        for (int g = 0; g < 4; g++) { \
            float4 b4 = *(const float4*)((bp) + dt*32 + 8*g + 4*l5); \
            ushort4 o; \
            o.x = to_bf16(ACC[4*g+0] + b4.x*(sc)); \
            o.y = to_bf16(ACC[4*g+1] + b4.y*(sc)); \
            o.z = to_bf16(ACC[4*g+2] + b4.z*(sc)); \
            o.w = to_bf16(ACC[4*g+3] + b4.w*(sc)); \
            *(ushort4*)(lds + (RB) + ((dt*6 + 2*(tt_) + l4)*4 + g)*256 + lr*16 + l5*8) = o; \
        } \
    } while (0)
// v epilogue: C[t=tt*32+8g+4*l5+r][d=dt*32+l31] -> V planes
#define V_EPI(ACC, tt_) do { \
        const float bvv_ = bv[dt*32 + l31]; \
        _Pragma("unroll") \
        for (int g = 0; g < 4; g++) { \
            ushort4 o; \
            o.x = to_bf16(ACC[4*g+0] + bvv_); \
            o.y = to_bf16(ACC[4*g+1] + bvv_); \
            o.z = to_bf16(ACC[4*g+2] + bvv_); \
            o.w = to_bf16(ACC[4*g+3] + bvv_); \
            *(ushort4*)(lds + VB + (((dt*3 + (tt_))*2 + l4)*4 + g)*256 + lr*16 + l5*8) = o; \
        } \
    } while (0)

    // ---- P0: stage Xq -> XB planes (bf16); prefetch Xk into regs ----
    #pragma unroll
    for (int c = 0; c < 3; c++) {
        const float* p = Xq + xoff + srow[c] * D_ + skc[c] * 8;
        float4 a0 = *(const float4*)p, a1 = *(const float4*)(p + 4);
        *(uint4*)(lds + XB + saddr[c]) = pack8(a0, a1);
    }
    float4 pf[6];
    #pragma unroll
    for (int c = 0; c < 3; c++) {
        const float* p = Xk + xoff + srow[c] * D_ + skc[c] * 8;
        pf[2*c] = *(const float4*)p; pf[2*c+1] = *(const float4*)(p + 4);
    }
    __syncthreads();                               // (0)

    // ---- P1: write Xk -> KB; prefetch Xv; q-GEMM(XB) + q-epi -> VB ----
    #pragma unroll
    for (int c = 0; c < 3; c++)
        *(uint4*)(lds + KB + saddr[c]) = pack8(pf[2*c], pf[2*c+1]);
    #pragma unroll
    for (int c = 0; c < 3; c++) {
        const float* p = Xv + xoff + srow[c] * D_ + skc[c] * 8;
        pf[2*c] = *(const float4*)p; pf[2*c+1] = *(const float4*)(p + 4);
    }
    {
        f32x16 a0 = (f32x16)0.f, a1 = (f32x16)0.f;
        #pragma unroll
        for (int ks = 0; ks < 16; ks++) {
            bf16x8 wf = WFRAG(W, ks);
            a0 = MFMA32(wf, XFRAG(XB, tt0, ks), a0);
            if (heavy) a1 = MFMA32(wf, XFRAG(XB, 2, ks), a1);
        }
        const float qs = 0.17677669529663687f;
        QK_EPI(a0, tt0, bq, qs, VB);
        if (heavy) QK_EPI(a1, 2, bq, qs, VB);
    }
    __syncthreads();                               // (1)

    // ---- P2: write Xv -> XB; qf pull(VB); k-GEMM(KB) [acc held] ----
    #pragma unroll
    for (int c = 0; c < 3; c++)
        *(uint4*)(lds + XB + saddr[c]) = pack8(pf[2*c], pf[2*c+1]);
    bf16x8 qf[3];
    #pragma unroll
    for (int j = 0; j < 3; j++)
        qf[j] = *(const bf16x8*)(lds + VB + ((h*6 + ib + j)*4 + kgl)*256 + lr*16);
    f32x16 k0 = (f32x16)0.f, k1 = (f32x16)0.f;
    {
        const ushort* Wk = W + WSZ;
        #pragma unroll
        for (int ks = 0; ks < 16; ks++) {
            bf16x8 wf = WFRAG(Wk, ks);
            k0 = MFMA32(wf, XFRAG(KB, tt0, ks), k0);
            if (heavy) k1 = MFMA32(wf, XFRAG(KB, 2, ks), k1);
        }
    }
    __syncthreads();                               // (2)

    // ---- P3: k-epi -> KB (Xk dead); v-GEMM(XB) + v-epi -> VB (q dead) ----
    QK_EPI(k0, tt0, bk, 1.0f, KB);
    if (heavy) QK_EPI(k1, 2, bk, 1.0f, KB);
    {
        const ushort* Wv = W + 2*WSZ;
        f32x16 a0 = (f32x16)0.f, a1 = (f32x16)0.f;
        #pragma unroll
        for (int ks = 0; ks < 16; ks++) {
            bf16x8 wf = WFRAG(Wv, ks);
            a0 = MFMA32(XFRAG(XB, tt0, ks), wf, a0);        // A = X (M=t)
            if (heavy) a1 = MFMA32(XFRAG(XB, 2, ks), wf, a1);
        }
        V_EPI(a0, tt0);
        if (heavy) V_EPI(a1, 2);
    }
    __syncthreads();                               // (3)

    // ---- P4: attention (R14-verbatim). head h, 3 q-row tiles; swapped
    //      QK^T, in-reg softmax, P via per-wave 3KB XB scratch, PV ----
    f32x4 oacc[3][2];
    #pragma unroll
    for (int j = 0; j < 3; j++) { oacc[j][0] = (f32x4)0.f; oacc[j][1] = (f32x4)0.f; }
    {
        char* sw = lds + XB + wv * 3072;           // 12 planes x 256B
        #pragma unroll
        for (int j = 0; j < 3; j++) {
            f32x4 s[6];
            #pragma unroll
            for (int mt = 0; mt < 6; mt++) {
                bf16x8 kf = *(const bf16x8*)(lds + KB + ((h*6+mt)*4+kgl)*256 + lr*16);
                s[mt] = MFMA16(kf, qf[j], (f32x4)0.f);   // rows kv, col q = lr
            }
            float mx = s[0][0];
            #pragma unroll
            for (int mt = 0; mt < 6; mt++)
                #pragma unroll
                for (int r = 0; r < 4; r++) mx = fmaxf(mx, s[mt][r]);
            mx = fmaxf(mx, __shfl_xor(mx, 16));
            mx = fmaxf(mx, __shfl_xor(mx, 32));
            float sum = 0.f;
            #pragma unroll
            for (int mt = 0; mt < 6; mt++)
                #pragma unroll
                for (int r = 0; r < 4; r++) {
                    float e = __expf(s[mt][r] - mx);
                    s[mt][r] = e; sum += e;
                }
            sum += __shfl_xor(sum, 16);
            sum += __shfl_xor(sum, 32);
            const float inv = 1.f / sum;
            #pragma unroll
            for (int mt = 0; mt < 6; mt++) {
                uint2 u2;
                u2.x = pack2(s[mt][0]*inv, s[mt][1]*inv);
                u2.y = pack2(s[mt][2]*inv, s[mt][3]*inv);
                *(uint2*)(sw + (mt*2 + (kgl>>1))*256 + lr*16 + (kgl&1)*8) = u2;
            }
            #pragma unroll
            for (int s2 = 0; s2 < 3; s2++) {
                bf16x8 pa = *(const bf16x8*)(sw + (s2*4+kgl)*256 + lr*16);
                #pragma unroll
                for (int n2 = 0; n2 < 2; n2++) {
                    bf16x8 vf = *(const bf16x8*)(lds + VB + (((h*3+s2)*2+n2)*4+kgl)*256 + lr*16);
                    oacc[j][n2] = MFMA16(pa, vf, oacc[j][n2]);
                }
            }
        }
    }
    __syncthreads();                               // (4) scratch dead

    // ---- P5: O -> XB planes (X layout), bf16 (R14-verbatim) ----
    #pragma unroll
    for (int j = 0; j < 3; j++)
        #pragma unroll
        for (int n2 = 0; n2 < 2; n2++) {
            const int dcol = h*32 + n2*16 + lr;
            const int kc   = dcol >> 3;            // 0..31
            const int irow = ib + j;
            char* base = lds + XB + (((kc>>2)*6 + irow)*4 + (kc&3))*256 + (dcol&7)*2;
            #pragma unroll
            for (int r = 0; r < 4; r++)
                *(ushort*)(base + (kgl*4+r)*16) = to_bf16(oacc[j][n2][r]);
        }
    __syncthreads();                               // (5)

    // ---- P6: wo GEMM(XB O planes, Wo) 32x32 -> d_out fp32 + bo ----
    {
        const ushort* Wo = W + 3*WSZ;
        f32x16 a0 = (f32x16)0.f, a1 = (f32x16)0.f;
        #pragma unroll
        for (int ks = 0; ks < 16; ks++) {
            bf16x8 wf = WFRAG(Wo, ks);
            a0 = MFMA32(XFRAG(XB, tt0, ks), wf, a0);        // A = O (M=t)
            if (heavy) a1 = MFMA32(XFRAG(XB, 2, ks), wf, a1);
        }
        const float bod = bo[dt*32 + l31];
        #pragma unroll
        for (int g = 0; g < 4; g++)
            #pragma unroll
            for (int r = 0; r < 4; r++) {
                const int t = tt0*32 + 8*g + 4*l5 + r;
                out[((size_t)(bn*T_ + t))*D_ + dt*32 + l31] = a0[4*g+r] + bod;
            }
        if (heavy) {
            #pragma unroll
            for (int g = 0; g < 4; g++)
                #pragma unroll
                for (int r = 0; r < 4; r++) {
                    const int t = 2*32 + 8*g + 4*l5 + r;
                    out[((size_t)(bn*T_ + t))*D_ + dt*32 + l31] = a1[4*g+r] + bod;
                }
        }
    }
#undef XFRAG
#undef WFRAG
#undef QK_EPI
#undef V_EPI
}

// ---------------------------------------------------------------------------
extern "C" void kernel_launch(void* const* d_in, const int* in_sizes, int n_in,
                              void* d_out, int out_size, void* d_ws, size_t ws_size,
                              hipStream_t stream)
{
    const float* query = (const float*)d_in[0];
    const float* key   = (const float*)d_in[1];
    const float* value = (const float*)d_in[2];
    // d_in[3..5]: pattern_matrix, Wp, bp -- mathematically a no-op (mask == 1)
    const float* Wq = (const float*)d_in[6];
    const float* bq = (const float*)d_in[7];
    const float* Wk = (const float*)d_in[8];
    const float* bk = (const float*)d_in[9];
    const float* Wv = (const float*)d_in[10];
    const float* bv = (const float*)d_in[11];
    const float* Wo = (const float*)d_in[12];
    const float* bo = (const float*)d_in[13];

    float*  out = (float*)d_out;
    ushort* whi = (ushort*)d_ws;   // 4 matrices, chunked bf16: 512 KB

    splitw_kernel<<<dim3(128), 256, 0, stream>>>(Wq, Wk, Wv, Wo, whi);
    mega_kernel<<<dim3(BN_), 1024, 0, stream>>>(
        query, key, value, whi, bq, bk, bv, bo, out);
}